// Round 10
// baseline (119.857 us; speedup 1.0000x reference)
//
#include <hip/hip_runtime.h>

#define NSEG 8192           // faces per set
#define NPTS (3 * NSEG)     // 24576 unified points [S | T | R]
#define NSUP 96             // 256-point super-tiles (32 per segment)
#define NXB  96             // one block per super-tile row; wave = 64 i-rows
#define NYG  25             // y-groups: g<24 -> Y=2g,2g+1; g==24 -> Y=48

typedef short bf16x8 __attribute__((ext_vector_type(8)));   // 8 bf16 (4 VGPRs)
typedef float f32x4  __attribute__((ext_vector_type(4)));   // 4 fp32 acc
typedef unsigned short u16;

__device__ __forceinline__ u16 f2bf(float x) {              // RNE f32 -> bf16 bits
    unsigned u = __builtin_bit_cast(unsigned, x);
    return (u16)((u + 0x7FFFu + ((u >> 16) & 1u)) >> 16);
}
__device__ __forceinline__ float bf2f(u16 h) {
    unsigned u = ((unsigned)h) << 16;
    return __builtin_bit_cast(float, u);
}

__device__ __forceinline__ void compute_point(
    int seg, int f,
    const float* __restrict__ sv, const int* __restrict__ si,
    const float* __restrict__ tv, const int* __restrict__ ti,
    const float* __restrict__ rn, const float* __restrict__ rc,
    float& cx, float& cy, float& cz, float& nx, float& ny, float& nz)
{
    if (seg == 2) {
        nx = rn[3*f];   ny = rn[3*f+1]; nz = rn[3*f+2];
        cx = rc[3*f];   cy = rc[3*f+1]; cz = rc[3*f+2];
    } else {
        const float* v  = (seg == 0) ? sv : tv;
        const int*   nd = (seg == 0) ? si : ti;
        int i0 = nd[3*f], i1 = nd[3*f+1], i2 = nd[3*f+2];
        float ax = v[3*i0], ay = v[3*i0+1], az = v[3*i0+2];
        float bx = v[3*i1], by = v[3*i1+1], bz = v[3*i1+2];
        float gx = v[3*i2], gy = v[3*i2+1], gz = v[3*i2+2];
        float ux = ax-bx, uy = ay-by, uz = az-bz;
        float wx = gx-bx, wy = gy-by, wz = gz-bz;
        nx = 0.5f*(uy*wz - uz*wy);
        ny = 0.5f*(uz*wx - ux*wz);
        nz = 0.5f*(ux*wy - uy*wx);
        cx = (ax+bx+gx)*(1.0f/3.0f);
        cy = (ay+by+gy)*(1.0f/3.0f);
        cz = (az+bz+gz)*(1.0f/3.0f);
    }
}

// Feature rows (K=16 bf16), hi/lo split: t = A_t . B_t = 1+|ci-cj|^2 (~1e-3 abs err).
// Interleaved records: A-side point = {at[16], an[16]} (64 B), B-side = {bt[16], bn[16]}.
__global__ void setup_feats(const float* __restrict__ sv, const int* __restrict__ si,
                            const float* __restrict__ tv, const int* __restrict__ ti,
                            const float* __restrict__ rn, const float* __restrict__ rc,
                            u16* __restrict__ ws, float* __restrict__ out) {
    int p = blockIdx.x * 256 + threadIdx.x;
    if (p == 0) out[0] = 0.0f;          // d_out poisoned 0xAA before every launch
    if (p >= NPTS) return;
    int seg = p >> 13, f = p & (NSEG - 1);
    float cx, cy, cz, nx, ny, nz;
    compute_point(seg, f, sv, si, tv, ti, rn, rc, cx, cy, cz, nx, ny, nz);

    const u16 ONE = 0x3F80;
    float s = cx*cx + cy*cy + cz*cz;
    u16 chx = f2bf(cx), chy = f2bf(cy), chz = f2bf(cz);
    u16 clx = f2bf(cx - bf2f(chx)), cly = f2bf(cy - bf2f(chy)), clz = f2bf(cz - bf2f(chz));
    u16 sh  = f2bf(s);
    u16 sl  = f2bf(s - bf2f(sh));
    u16 m2hx = f2bf(-2.0f*bf2f(chx)), m2hy = f2bf(-2.0f*bf2f(chy)), m2hz = f2bf(-2.0f*bf2f(chz));
    u16 m2lx = f2bf(-2.0f*bf2f(clx)), m2ly = f2bf(-2.0f*bf2f(cly)), m2lz = f2bf(-2.0f*bf2f(clz));
    u16 nhx = f2bf(nx), nhy = f2bf(ny), nhz = f2bf(nz);
    u16 nlx = f2bf(nx - bf2f(nhx)), nly = f2bf(ny - bf2f(nhy)), nlz = f2bf(nz - bf2f(nhz));

    u16 at[16] = {chx,chy,chz, clx,cly,clz, chx,chy,chz, sh, sl, ONE, ONE, ONE, 0, 0};
    u16 bt[16] = {m2hx,m2hy,m2hz, m2hx,m2hy,m2hz, m2lx,m2ly,m2lz, ONE, ONE, sh, sl, ONE, 0, 0};
    u16 an[16] = {nhx,nhy,nhz, nlx,nly,nlz, nhx,nhy,nhz, 0,0,0,0,0,0,0};
    u16 bn[16] = {nhx,nhy,nhz, nhx,nhy,nhz, nlx,nly,nlz, 0,0,0,0,0,0,0};

    bf16x8* A8 = (bf16x8*)ws;            // A-record: frags [at0 at1 an0 an1] per point
    bf16x8* B8 = A8 + (size_t)NPTS*4;    // B-record: frags [bt0 bt1 bn0 bn1] per point
    bf16x8 v0, v1, v2, v3;
    #pragma unroll
    for (int k = 0; k < 8; ++k) { v0[k] = (short)at[k]; v1[k] = (short)at[k+8];
                                  v2[k] = (short)an[k]; v3[k] = (short)an[k+8]; }
    A8[(size_t)p*4+0] = v0; A8[(size_t)p*4+1] = v1; A8[(size_t)p*4+2] = v2; A8[(size_t)p*4+3] = v3;
    #pragma unroll
    for (int k = 0; k < 8; ++k) { v0[k] = (short)bt[k]; v1[k] = (short)bt[k+8];
                                  v2[k] = (short)bn[k]; v3[k] = (short)bn[k+8]; }
    B8[(size_t)p*4+0] = v0; B8[(size_t)p*4+1] = v1; B8[(size_t)p*4+2] = v2; B8[(size_t)p*4+3] = v3;
}

// Symmetric-pair kernel. R18: MFMA shape switch 32x32x16 -> 16x16x32 bf16,
// K zero-padded on the A side (features are K=16; lanes kg>=2 hold k16..31 = 0,
// so B-side kg 2/3 garbage is annihilated). WHY: R17 accounting showed the two
// f32x16 accumulators live in AGPRs (VGPR_Count=64) -> every EPI consume is a
// v_accvgpr_read, ~64 extra VALU insts/jt (~12 us), plus 16-reg Z init. The
// f32x4 accumulators of 16x16x32 stay VGPR-resident: zero accvgpr traffic,
// smaller waves. EPI instruction count unchanged (same pairs/lane); MFMA
// cycles rise ~2.5x (half K wasted) against a 14%-busy matrix pipe.
// Fragment map (family rule, validated by the working 32x32 kernel):
//   A: row = lane&15, k = (lane>>4)*8 + j   (kg 0/1 = record frags 0/1)
//   B: col = lane&15, k = (lane>>4)*8 + j   (kg&1 reuse; killed by A zeros)
// C/D layout irrelevant: all 4 outputs are distinct (i,j) pairs, summed.
// Per wave: 4x 16-row i-tiles (rows wid*64+{0,16,32,48}); 16 j16-tiles per y.
// No manual prefetch rotation (every spill this session came from manual
// pipelining; unroll-2 + TLP schedules the 2 loads ahead).
// Accumulation regrouping shifts f32 rounding ~1e-7 rel (bf16 features ~1e-3).
// Wrapped map over 256-pt super-tiles: (I,J) = (X, (X+Y)%96); mult = 2 except
// Y==0 (diagonal, once) and Y==48 (hit from both ends) -> 96+96+96*47*2 = 96^2. ✓
__launch_bounds__(256, 2)
__global__ void energy_mfma(const u16* __restrict__ ws, float* __restrict__ out) {
    const int tid  = threadIdx.x;
    const int lane = tid & 63, wid = tid >> 6;
    const int l15 = lane & 15;
    const int kg  = lane >> 4;               // k-group 0..3 (8 k each)
    const int kgb = kg & 1;                  // B-side frag reuse for kg 2/3

    const int X  = blockIdx.x;               // 0..95 (super-tile row)
    const int g  = blockIdx.y;               // 0..24
    const int y0  = (g < 24) ? 2*g : 48;
    const int ycnt = (g < 24) ? 2 : 1;
    const int gi = X >> 5;                   // 32 super-tiles per segment

    const bf16x8* A8 = (const bf16x8*)ws;
    const bf16x8* B8 = A8 + (size_t)NPTS*4;

    // 4 persistent 16-row i-tiles: rows X*256 + wid*64 + it*16 + l15
    bf16x8 zero8 = (bf16x8){0,0,0,0,0,0,0,0};
    const int pbase = (X*256 + wid*64 + l15) * 4;    // frag idx of i-tile 0 row
    bf16x8 at0, an0, at1, an1, at2, an2, at3, an3;
    if (kg < 2) {                                    // kg 0/1: real k 0-7 / 8-15
        at0 = A8[pbase + kg];        an0 = A8[pbase + 2 + kg];
        at1 = A8[pbase + 64 + kg];   an1 = A8[pbase + 66 + kg];   // +16 pts * 4
        at2 = A8[pbase + 128 + kg];  an2 = A8[pbase + 130 + kg];
        at3 = A8[pbase + 192 + kg];  an3 = A8[pbase + 194 + kg];
    } else {                                         // kg 2/3: zero-padded K
        at0 = an0 = at1 = an1 = at2 = an2 = at3 = an3 = zero8;
    }

    f32x4 Z = {0.0f, 0.0f, 0.0f, 0.0f};

    const int lofsB = l15*4 + kgb;           // per-lane frag offset in a j16-tile

    // per-y addressing + weight (block-uniform), branchless (no indexed array)
    auto yinfo = [&](int y, int& vo, float& w) {
        int J = X + y; if (J >= NSUP) J -= NSUP;
        int jg = J >> 5;
        float base_w;
        if (gi == jg)                 base_w = (gi == 2) ? 2.0f : 1.8f;
        else if (gi == 2 || jg == 2)  base_w = -1.0f;
        else                          base_w = -0.8f;
        const float mult = (y == 0 || y == 48) ? 1.0f : 2.0f;
        w = base_w * mult;
        vo = J*1024 + lofsB;                 // frag idx: 4/point, 64/j16-tile
    };

    // one 16x16 pair-tile: 2 MFMAs + 13-VALU EPI quad (same math as before)
#define EPIQ(AT, AN, TS) do {                                                 \
        f32x4 ct = __builtin_amdgcn_mfma_f32_16x16x32_bf16(AT, bt, Z, 0,0,0); \
        f32x4 cn = __builtin_amdgcn_mfma_f32_16x16x32_bf16(AN, bn, Z, 0,0,0); \
        float q0 = ct[0]*ct[0], q1 = ct[1]*ct[1];                             \
        float q2 = ct[2]*ct[2], q3 = ct[3]*ct[3];                             \
        float s01 = q0*q1, s23 = q2*q3;                                       \
        float r   = __builtin_amdgcn_rcpf(s01*s23);                           \
        float u   = __builtin_fmaf(cn[1], q0, cn[0]*q1);                      \
        float v   = __builtin_fmaf(cn[3], q2, cn[2]*q3);                      \
        float num = __builtin_fmaf(v, s01, u*s23);                            \
        TS = __builtin_fmaf(num, r, TS);                                      \
    } while (0)

    float acc = 0.0f;
    #pragma unroll 1
    for (int yy = 0; yy < ycnt; ++yy) {
        int vo; float w;
        yinfo(y0 + yy, vo, w);

        float ts0 = 0.0f, ts1 = 0.0f;
        #pragma unroll 2
        for (int j16 = 0; j16 < 16; ++j16) {
            bf16x8 bt = B8[vo + j16*64];
            bf16x8 bn = B8[vo + j16*64 + 2];
            EPIQ(at0, an0, ts0);
            EPIQ(at1, an1, ts1);
            EPIQ(at2, an2, ts0);
            EPIQ(at3, an3, ts1);
        }
        acc = __builtin_fmaf(w, ts0 + ts1, acc);
    }
#undef EPIQ

    // wave shuffle reduce -> 4 partials -> one atomic per block
    for (int off = 32; off; off >>= 1) acc += __shfl_down(acc, off, 64);
    __shared__ float partial[4];
    if ((tid & 63) == 0) partial[wid] = acc;
    __syncthreads();
    if (tid == 0)
        atomicAdd(out, (partial[0] + partial[1]) + (partial[2] + partial[3]));
}

extern "C" void kernel_launch(void* const* d_in, const int* in_sizes, int n_in,
                              void* d_out, int out_size, void* d_ws, size_t ws_size,
                              hipStream_t stream) {
    const float* sv = (const float*)d_in[0];
    const int*   si = (const int*)d_in[1];
    const float* tv = (const float*)d_in[2];
    const int*   ti = (const int*)d_in[3];
    const float* rn = (const float*)d_in[4];
    const float* rc = (const float*)d_in[5];
    float* out = (float*)d_out;
    u16*   ws  = (u16*)d_ws;                      // 2 x 24576 x 64 B = 3 MB features

    setup_feats<<<NPTS/256, 256, 0, stream>>>(sv, si, tv, ti, rn, rc, ws, out);
    dim3 grid(NXB, NYG);                          // 96 x 25 = 2400 blocks of 256
    energy_mfma<<<grid, 256, 0, stream>>>(ws, out);
}

// Round 11
// 115.943 us; speedup vs baseline: 1.0338x; 1.0338x over previous
//
#include <hip/hip_runtime.h>

#define NSEG 8192           // faces per set
#define NPTS (3 * NSEG)     // 24576 unified points [S | T | R]
#define NSUP 96             // 256-point super-tiles (32 per segment)
#define NXB  96             // one block per super-tile row (2 i-tiles/wave)
#define NYG  25             // y-groups: g<24 -> Y=2g,2g+1; g==24 -> Y=48

typedef short bf16x8 __attribute__((ext_vector_type(8)));   // 8 bf16 (4 VGPRs)
typedef float f32x16 __attribute__((ext_vector_type(16)));  // 16 fp32 acc
typedef float f32x2  __attribute__((ext_vector_type(2)));   // packed-f32 pair
typedef unsigned short u16;

__device__ __forceinline__ u16 f2bf(float x) {              // RNE f32 -> bf16 bits
    unsigned u = __builtin_bit_cast(unsigned, x);
    return (u16)((u + 0x7FFFu + ((u >> 16) & 1u)) >> 16);
}
__device__ __forceinline__ float bf2f(u16 h) {
    unsigned u = ((unsigned)h) << 16;
    return __builtin_bit_cast(float, u);
}

__device__ __forceinline__ void compute_point(
    int seg, int f,
    const float* __restrict__ sv, const int* __restrict__ si,
    const float* __restrict__ tv, const int* __restrict__ ti,
    const float* __restrict__ rn, const float* __restrict__ rc,
    float& cx, float& cy, float& cz, float& nx, float& ny, float& nz)
{
    if (seg == 2) {
        nx = rn[3*f];   ny = rn[3*f+1]; nz = rn[3*f+2];
        cx = rc[3*f];   cy = rc[3*f+1]; cz = rc[3*f+2];
    } else {
        const float* v  = (seg == 0) ? sv : tv;
        const int*   nd = (seg == 0) ? si : ti;
        int i0 = nd[3*f], i1 = nd[3*f+1], i2 = nd[3*f+2];
        float ax = v[3*i0], ay = v[3*i0+1], az = v[3*i0+2];
        float bx = v[3*i1], by = v[3*i1+1], bz = v[3*i1+2];
        float gx = v[3*i2], gy = v[3*i2+1], gz = v[3*i2+2];
        float ux = ax-bx, uy = ay-by, uz = az-bz;
        float wx = gx-bx, wy = gy-by, wz = gz-bz;
        nx = 0.5f*(uy*wz - uz*wy);
        ny = 0.5f*(uz*wx - ux*wz);
        nz = 0.5f*(ux*wy - uy*wx);
        cx = (ax+bx+gx)*(1.0f/3.0f);
        cy = (ay+by+gy)*(1.0f/3.0f);
        cz = (az+bz+gz)*(1.0f/3.0f);
    }
}

// Feature rows (K=16 bf16), hi/lo split: t = A_t . B_t = 1+|ci-cj|^2 (~1e-3 abs err).
// Interleaved records: A-side point = {at[16], an[16]} (64 B), B-side = {bt[16], bn[16]}.
__global__ void setup_feats(const float* __restrict__ sv, const int* __restrict__ si,
                            const float* __restrict__ tv, const int* __restrict__ ti,
                            const float* __restrict__ rn, const float* __restrict__ rc,
                            u16* __restrict__ ws, float* __restrict__ out) {
    int p = blockIdx.x * 256 + threadIdx.x;
    if (p == 0) out[0] = 0.0f;          // d_out poisoned 0xAA before every launch
    if (p >= NPTS) return;
    int seg = p >> 13, f = p & (NSEG - 1);
    float cx, cy, cz, nx, ny, nz;
    compute_point(seg, f, sv, si, tv, ti, rn, rc, cx, cy, cz, nx, ny, nz);

    const u16 ONE = 0x3F80;
    float s = cx*cx + cy*cy + cz*cz;
    u16 chx = f2bf(cx), chy = f2bf(cy), chz = f2bf(cz);
    u16 clx = f2bf(cx - bf2f(chx)), cly = f2bf(cy - bf2f(chy)), clz = f2bf(cz - bf2f(chz));
    u16 sh  = f2bf(s);
    u16 sl  = f2bf(s - bf2f(sh));
    u16 m2hx = f2bf(-2.0f*bf2f(chx)), m2hy = f2bf(-2.0f*bf2f(chy)), m2hz = f2bf(-2.0f*bf2f(chz));
    u16 m2lx = f2bf(-2.0f*bf2f(clx)), m2ly = f2bf(-2.0f*bf2f(cly)), m2lz = f2bf(-2.0f*bf2f(clz));
    u16 nhx = f2bf(nx), nhy = f2bf(ny), nhz = f2bf(nz);
    u16 nlx = f2bf(nx - bf2f(nhx)), nly = f2bf(ny - bf2f(nhy)), nlz = f2bf(nz - bf2f(nhz));

    u16 at[16] = {chx,chy,chz, clx,cly,clz, chx,chy,chz, sh, sl, ONE, ONE, ONE, 0, 0};
    u16 bt[16] = {m2hx,m2hy,m2hz, m2hx,m2hy,m2hz, m2lx,m2ly,m2lz, ONE, ONE, sh, sl, ONE, 0, 0};
    u16 an[16] = {nhx,nhy,nhz, nlx,nly,nlz, nhx,nhy,nhz, 0,0,0,0,0,0,0};
    u16 bn[16] = {nhx,nhy,nhz, nhx,nhy,nhz, nlx,nly,nlz, 0,0,0,0,0,0,0};

    bf16x8* A8 = (bf16x8*)ws;            // A-record: frags [at0 at1 an0 an1] per point
    bf16x8* B8 = A8 + (size_t)NPTS*4;    // B-record: frags [bt0 bt1 bn0 bn1] per point
    bf16x8 v0, v1, v2, v3;
    #pragma unroll
    for (int k = 0; k < 8; ++k) { v0[k] = (short)at[k]; v1[k] = (short)at[k+8];
                                  v2[k] = (short)an[k]; v3[k] = (short)an[k+8]; }
    A8[(size_t)p*4+0] = v0; A8[(size_t)p*4+1] = v1; A8[(size_t)p*4+2] = v2; A8[(size_t)p*4+3] = v3;
    #pragma unroll
    for (int k = 0; k < 8; ++k) { v0[k] = (short)bt[k]; v1[k] = (short)bt[k+8];
                                  v2[k] = (short)bn[k]; v3[k] = (short)bn[k+8]; }
    B8[(size_t)p*4+0] = v0; B8[(size_t)p*4+1] = v1; B8[(size_t)p*4+2] = v2; B8[(size_t)p*4+3] = v3;
}

// Symmetric-pair kernel. R19 = R17 structure (best measured: 53.4 us; 32x32x16
// MFMA, 2 i-tiles/wave, NYG=25, (256,2)) + two VALU cuts. R18 falsified the
// accvgpr theory (f32x4 VGPR accs gave the SAME VALU time) and regressed via
// 2x MFMA cycles -> reverted shape. Cuts:
//  (1) direct-indexed jt loads under unroll 4 (kills 16 v_mov/jt rotation +
//      pofs select; the compiler hoists/pipelines — R18-proven load pattern).
//  (2) pk-f32 EPI: acc elements ct[4q],ct[4q+1] are consecutive MFMA-dst regs,
//      so float2 views cost nothing; q-squares and cn*q products become
//      v_pk_mul_f32 (4 pk replace 8 scalar; swap via op_sel). 14->12 issue
//      slots per quad. u/v rounding: mul+fma -> 2mul+add (same error class as
//      the existing ~1e-3 bf16 feature error).
// EPI floor ~13.7 us (308M deduped pairs x 3.5i x 2cyc / 1024 SIMD).
// Wrapped map over 256-pt super-tiles: (I,J) = (X, (X+Y)%96); mult = 2 except
// Y==0 (diagonal, once) and Y==48 (hit from both ends) -> 96+96+96*47*2 = 96^2. ✓
__launch_bounds__(256, 2)
__global__ void energy_mfma(const u16* __restrict__ ws, float* __restrict__ out) {
    const int tid  = threadIdx.x;
    const int lane = tid & 63, wid = tid >> 6;
    const int half = lane >> 5, r32 = lane & 31;

    const int X  = blockIdx.x;                // 0..95 (super-tile row)
    const int g  = blockIdx.y;                // 0..24
    const int y0  = (g < 24) ? 2*g : 48;
    const int ycnt = (g < 24) ? 2 : 1;
    const int gi = X >> 5;                    // 32 super-tiles per segment

    const bf16x8* A8 = (const bf16x8*)ws;
    const bf16x8* B8 = A8 + (size_t)NPTS*4;

    // two persistent 32-row i-tiles per wave: rows pi and pi+128
    const int pi = X*256 + wid*32 + r32;
    const bf16x8 at0 = A8[pi*4 + half];
    const bf16x8 an0 = A8[pi*4 + 2 + half];
    const bf16x8 at1 = A8[pi*4 + 512 + half];        // +128 points * 4 frags
    const bf16x8 an1 = A8[pi*4 + 514 + half];

    f32x16 Z;
    #pragma unroll
    for (int k = 0; k < 16; ++k) Z[k] = 0.0f;

    const int lofs = r32*4 + half;            // per-lane frag offset within a j-tile

    // per-y addressing + weight (block-uniform), branchless (no indexed array)
    auto yinfo = [&](int y, int& vo, float& w) {
        int J = X + y; if (J >= NSUP) J -= NSUP;
        int jg = J >> 5;
        float base_w;
        if (gi == jg)                 base_w = (gi == 2) ? 2.0f : 1.8f;
        else if (gi == 2 || jg == 2)  base_w = -1.0f;
        else                          base_w = -0.8f;
        const float mult = (y == 0 || y == 48) ? 1.0f : 2.0f;
        w = base_w * mult;
        vo = J*1024 + lofs;                   // frag index: stride 4/point, 128/j-tile
    };

    // pk-f32 EPI: one v_rcp per 4 pairs; float2 views of adjacent acc elements
#define EPI(CT, CN, TS0, TS1) do {                                            \
        _Pragma("unroll")                                                     \
        for (int gq = 0; gq < 4; ++gq) {                                      \
            f32x2 t01 = {CT[4*gq+0], CT[4*gq+1]};                             \
            f32x2 t23 = {CT[4*gq+2], CT[4*gq+3]};                             \
            f32x2 cA  = {CN[4*gq+0], CN[4*gq+1]};                             \
            f32x2 cB  = {CN[4*gq+2], CN[4*gq+3]};                             \
            f32x2 qA = t01*t01, qB = t23*t23;        /* v_pk_mul_f32 x2 */    \
            float s01 = qA[0]*qA[1], s23 = qB[0]*qB[1];                       \
            float r   = __builtin_amdgcn_rcpf(s01*s23);                       \
            f32x2 sqA = {qA[1], qA[0]}, sqB = {qB[1], qB[0]};                 \
            f32x2 pA = cA*sqA, pB = cB*sqB;          /* pk_mul + op_sel */    \
            float u = pA[0] + pA[1];                                          \
            float v = pB[0] + pB[1];                                          \
            float num = __builtin_fmaf(v, s01, u*s23);                        \
            if (gq & 1) TS1 = __builtin_fmaf(num, r, TS1);                    \
            else        TS0 = __builtin_fmaf(num, r, TS0);                    \
        }                                                                     \
    } while (0)

    float acc = 0.0f;
    #pragma unroll 1
    for (int yy = 0; yy < ycnt; ++yy) {
        int vo; float w;
        yinfo(y0 + yy, vo, w);

        float tsA0 = 0.0f, tsA1 = 0.0f;       // i-tile 0 partials
        float tsB0 = 0.0f, tsB1 = 0.0f;       // i-tile 1 partials
        #pragma unroll 4
        for (int jt = 0; jt < 8; ++jt) {
            bf16x8 bt = B8[vo + jt*128];      // direct index, no rotation
            bf16x8 bn = B8[vo + jt*128 + 2];

            f32x16 ct, cn;
            ct = __builtin_amdgcn_mfma_f32_32x32x16_bf16(at0, bt, Z, 0, 0, 0);
            cn = __builtin_amdgcn_mfma_f32_32x32x16_bf16(an0, bn, Z, 0, 0, 0);
            EPI(ct, cn, tsA0, tsA1);
            ct = __builtin_amdgcn_mfma_f32_32x32x16_bf16(at1, bt, Z, 0, 0, 0);
            cn = __builtin_amdgcn_mfma_f32_32x32x16_bf16(an1, bn, Z, 0, 0, 0);
            EPI(ct, cn, tsB0, tsB1);
        }
        acc = __builtin_fmaf(w, tsA0 + tsA1, acc);
        acc = __builtin_fmaf(w, tsB0 + tsB1, acc);
    }
#undef EPI

    // wave shuffle reduce -> 4 partials -> one atomic per block
    for (int off = 32; off; off >>= 1) acc += __shfl_down(acc, off, 64);
    __shared__ float partial[4];
    if ((tid & 63) == 0) partial[wid] = acc;
    __syncthreads();
    if (tid == 0)
        atomicAdd(out, (partial[0] + partial[1]) + (partial[2] + partial[3]));
}

extern "C" void kernel_launch(void* const* d_in, const int* in_sizes, int n_in,
                              void* d_out, int out_size, void* d_ws, size_t ws_size,
                              hipStream_t stream) {
    const float* sv = (const float*)d_in[0];
    const int*   si = (const int*)d_in[1];
    const float* tv = (const float*)d_in[2];
    const int*   ti = (const int*)d_in[3];
    const float* rn = (const float*)d_in[4];
    const float* rc = (const float*)d_in[5];
    float* out = (float*)d_out;
    u16*   ws  = (u16*)d_ws;                      // 2 x 24576 x 64 B = 3 MB features

    setup_feats<<<NPTS/256, 256, 0, stream>>>(sv, si, tv, ti, rn, rc, ws, out);
    dim3 grid(NXB, NYG);                          // 96 x 25 = 2400 blocks of 256
    energy_mfma<<<grid, 256, 0, stream>>>(ws, out);
}

// Round 12
// 111.973 us; speedup vs baseline: 1.0704x; 1.0355x over previous
//
#include <hip/hip_runtime.h>

#define NSEG 8192           // faces per set
#define NPTS (3 * NSEG)     // 24576 unified points [S | T | R]
#define NSUP 96             // 256-point super-tiles (32 per segment)
#define NXB  96             // one block per super-tile row (2 i-tiles/wave)
#define NYG  25             // y-groups: g<24 -> Y=2g,2g+1; g==24 -> Y=48

typedef short bf16x8 __attribute__((ext_vector_type(8)));   // 8 bf16 (4 VGPRs)
typedef float f32x16 __attribute__((ext_vector_type(16)));  // 16 fp32 acc
typedef unsigned short u16;

__device__ __forceinline__ u16 f2bf(float x) {              // RNE f32 -> bf16 bits
    unsigned u = __builtin_bit_cast(unsigned, x);
    return (u16)((u + 0x7FFFu + ((u >> 16) & 1u)) >> 16);
}
__device__ __forceinline__ float bf2f(u16 h) {
    unsigned u = ((unsigned)h) << 16;
    return __builtin_bit_cast(float, u);
}

__device__ __forceinline__ void compute_point(
    int seg, int f,
    const float* __restrict__ sv, const int* __restrict__ si,
    const float* __restrict__ tv, const int* __restrict__ ti,
    const float* __restrict__ rn, const float* __restrict__ rc,
    float& cx, float& cy, float& cz, float& nx, float& ny, float& nz)
{
    if (seg == 2) {
        nx = rn[3*f];   ny = rn[3*f+1]; nz = rn[3*f+2];
        cx = rc[3*f];   cy = rc[3*f+1]; cz = rc[3*f+2];
    } else {
        const float* v  = (seg == 0) ? sv : tv;
        const int*   nd = (seg == 0) ? si : ti;
        int i0 = nd[3*f], i1 = nd[3*f+1], i2 = nd[3*f+2];
        float ax = v[3*i0], ay = v[3*i0+1], az = v[3*i0+2];
        float bx = v[3*i1], by = v[3*i1+1], bz = v[3*i1+2];
        float gx = v[3*i2], gy = v[3*i2+1], gz = v[3*i2+2];
        float ux = ax-bx, uy = ay-by, uz = az-bz;
        float wx = gx-bx, wy = gy-by, wz = gz-bz;
        nx = 0.5f*(uy*wz - uz*wy);
        ny = 0.5f*(uz*wx - ux*wz);
        nz = 0.5f*(ux*wy - uy*wx);
        cx = (ax+bx+gx)*(1.0f/3.0f);
        cy = (ay+by+gy)*(1.0f/3.0f);
        cz = (az+bz+gz)*(1.0f/3.0f);
    }
}

// Feature rows (K=16 bf16), hi/lo split: t = A_t . B_t = 1+|ci-cj|^2 (~1e-3 abs err).
// Interleaved records: A-side point = {at[16], an[16]} (64 B), B-side = {bt[16], bn[16]}.
__global__ void setup_feats(const float* __restrict__ sv, const int* __restrict__ si,
                            const float* __restrict__ tv, const int* __restrict__ ti,
                            const float* __restrict__ rn, const float* __restrict__ rc,
                            u16* __restrict__ ws, float* __restrict__ out) {
    int p = blockIdx.x * 256 + threadIdx.x;
    if (p == 0) out[0] = 0.0f;          // d_out poisoned 0xAA before every launch
    if (p >= NPTS) return;
    int seg = p >> 13, f = p & (NSEG - 1);
    float cx, cy, cz, nx, ny, nz;
    compute_point(seg, f, sv, si, tv, ti, rn, rc, cx, cy, cz, nx, ny, nz);

    const u16 ONE = 0x3F80;
    float s = cx*cx + cy*cy + cz*cz;
    u16 chx = f2bf(cx), chy = f2bf(cy), chz = f2bf(cz);
    u16 clx = f2bf(cx - bf2f(chx)), cly = f2bf(cy - bf2f(chy)), clz = f2bf(cz - bf2f(chz));
    u16 sh  = f2bf(s);
    u16 sl  = f2bf(s - bf2f(sh));
    u16 m2hx = f2bf(-2.0f*bf2f(chx)), m2hy = f2bf(-2.0f*bf2f(chy)), m2hz = f2bf(-2.0f*bf2f(chz));
    u16 m2lx = f2bf(-2.0f*bf2f(clx)), m2ly = f2bf(-2.0f*bf2f(cly)), m2lz = f2bf(-2.0f*bf2f(clz));
    u16 nhx = f2bf(nx), nhy = f2bf(ny), nhz = f2bf(nz);
    u16 nlx = f2bf(nx - bf2f(nhx)), nly = f2bf(ny - bf2f(nhy)), nlz = f2bf(nz - bf2f(nhz));

    u16 at[16] = {chx,chy,chz, clx,cly,clz, chx,chy,chz, sh, sl, ONE, ONE, ONE, 0, 0};
    u16 bt[16] = {m2hx,m2hy,m2hz, m2hx,m2hy,m2hz, m2lx,m2ly,m2lz, ONE, ONE, sh, sl, ONE, 0, 0};
    u16 an[16] = {nhx,nhy,nhz, nlx,nly,nlz, nhx,nhy,nhz, 0,0,0,0,0,0,0};
    u16 bn[16] = {nhx,nhy,nhz, nhx,nhy,nhz, nlx,nly,nlz, 0,0,0,0,0,0,0};

    bf16x8* A8 = (bf16x8*)ws;            // A-record: frags [at0 at1 an0 an1] per point
    bf16x8* B8 = A8 + (size_t)NPTS*4;    // B-record: frags [bt0 bt1 bn0 bn1] per point
    bf16x8 v0, v1, v2, v3;
    #pragma unroll
    for (int k = 0; k < 8; ++k) { v0[k] = (short)at[k]; v1[k] = (short)at[k+8];
                                  v2[k] = (short)an[k]; v3[k] = (short)an[k+8]; }
    A8[(size_t)p*4+0] = v0; A8[(size_t)p*4+1] = v1; A8[(size_t)p*4+2] = v2; A8[(size_t)p*4+3] = v3;
    #pragma unroll
    for (int k = 0; k < 8; ++k) { v0[k] = (short)bt[k]; v1[k] = (short)bt[k+8];
                                  v2[k] = (short)bn[k]; v3[k] = (short)bn[k+8]; }
    B8[(size_t)p*4+0] = v0; B8[(size_t)p*4+1] = v1; B8[(size_t)p*4+2] = v2; B8[(size_t)p*4+3] = v3;
}

// Symmetric-pair kernel. R20 = R17 BYTE-FOR-BYTE (best: 53.4 us; 32x32x16,
// 2 i-tiles/wave, depth-2 rotation, NYG=25) with __launch_bounds__(256,4).
// WHY: across R9-R19 the VALU-busy time is invariant at ~34+-1.5 us whatever
// the structure — all dur differences are idle. Residency tracks the
// launch-bounds hint, not actual registers: (256,3) rounds sustained ~4.3
// waves/SIMD, ALL (256,2) rounds ~2.6-3.3 (even R18 with VGPR=56 and no AGPR
// pressure). R17's unified footprint ~112 regs fits the 4-waves/EU budget
// (128/wave), so (256,4) should ~double residency and cut the ~19 us idle.
// Gate: WRITE_SIZE must stay ~75 B (spill -> revert, declare floor).
// Accumulation order within (X,y,jt,gq,i-tile) unchanged -> bitwise-same energy.
// Wrapped map over 256-pt super-tiles: (I,J) = (X, (X+Y)%96); mult = 2 except
// Y==0 (diagonal, once) and Y==48 (hit from both ends) -> 96+96+96*47*2 = 96^2. ✓
__launch_bounds__(256, 4)
__global__ void energy_mfma(const u16* __restrict__ ws, float* __restrict__ out) {
    const int tid  = threadIdx.x;
    const int lane = tid & 63, wid = tid >> 6;
    const int half = lane >> 5, r32 = lane & 31;

    const int X  = blockIdx.x;                // 0..95 (super-tile row)
    const int g  = blockIdx.y;                // 0..24
    const int y0  = (g < 24) ? 2*g : 48;
    const int ycnt = (g < 24) ? 2 : 1;
    const int gi = X >> 5;                    // 32 super-tiles per segment

    const bf16x8* A8 = (const bf16x8*)ws;
    const bf16x8* B8 = A8 + (size_t)NPTS*4;

    // two persistent 32-row i-tiles per wave: rows pi and pi+128
    const int pi = X*256 + wid*32 + r32;
    const bf16x8 at0 = A8[pi*4 + half];
    const bf16x8 an0 = A8[pi*4 + 2 + half];
    const bf16x8 at1 = A8[pi*4 + 512 + half];        // +128 points * 4 frags
    const bf16x8 an1 = A8[pi*4 + 514 + half];

    f32x16 Z;
    #pragma unroll
    for (int k = 0; k < 16; ++k) Z[k] = 0.0f;

    const int lofs = r32*4 + half;            // per-lane frag offset within a j-tile

    // per-y addressing + weight (block-uniform), branchless (no indexed array)
    auto yinfo = [&](int y, int& vo, float& w) {
        int J = X + y; if (J >= NSUP) J -= NSUP;
        int jg = J >> 5;
        float base_w;
        if (gi == jg)                 base_w = (gi == 2) ? 2.0f : 1.8f;
        else if (gi == 2 || jg == 2)  base_w = -1.0f;
        else                          base_w = -0.8f;
        const float mult = (y == 0 || y == 48) ? 1.0f : 2.0f;
        w = base_w * mult;
        vo = J*1024 + lofs;                   // frag index: stride 4/point, 128/j-tile
    };

    // batched rcp: one v_rcp per 4 pairs; two independent partial chains
#define EPI(CT, CN, TS0, TS1) do {                                            \
        _Pragma("unroll")                                                     \
        for (int gq = 0; gq < 4; ++gq) {                                      \
            float t0 = CT[4*gq+0], t1 = CT[4*gq+1];                           \
            float t2 = CT[4*gq+2], t3 = CT[4*gq+3];                           \
            float q0 = t0*t0, q1 = t1*t1, q2 = t2*t2, q3 = t3*t3;             \
            float s01 = q0*q1, s23 = q2*q3;                                   \
            float r   = __builtin_amdgcn_rcpf(s01*s23);                       \
            float u   = __builtin_fmaf(CN[4*gq+1], q0, CN[4*gq+0]*q1);        \
            float v   = __builtin_fmaf(CN[4*gq+3], q2, CN[4*gq+2]*q3);        \
            float num = __builtin_fmaf(v, s01, u*s23);                        \
            if (gq & 1) TS1 = __builtin_fmaf(num, r, TS1);                    \
            else        TS0 = __builtin_fmaf(num, r, TS0);                    \
        }                                                                     \
    } while (0)

    float acc = 0.0f;
    int vo; float w;
    yinfo(y0, vo, w);

    // prologue: tiles 0 and 1 of the first y in flight (depth-2 pipeline)
    bf16x8 bt0 = B8[vo],       bn0 = B8[vo + 2];
    bf16x8 bt1 = B8[vo + 128], bn1 = B8[vo + 130];

    #pragma unroll 1
    for (int yy = 0; yy < ycnt; ++yy) {
        // next-y addressing (clamped on the last y -> harmless redundant loads)
        int von; float wn;
        yinfo((yy + 1 < ycnt) ? (y0 + yy + 1) : (y0 + yy), von, wn);

        float tsA0 = 0.0f, tsA1 = 0.0f;       // i-tile 0 partials
        float tsB0 = 0.0f, tsB1 = 0.0f;       // i-tile 1 partials
        #pragma unroll 2
        for (int jt = 0; jt < 8; ++jt) {
            // prefetch tile jt+2 (tiles 6/7 fetch next-y tiles 0/1)
            const int pofs = (jt < 6) ? (vo + (jt + 2)*128) : (von + (jt - 6)*128);
            bf16x8 pt = B8[pofs];
            bf16x8 pn = B8[pofs + 2];

            f32x16 ct, cn;
            ct = __builtin_amdgcn_mfma_f32_32x32x16_bf16(at0, bt0, Z, 0, 0, 0);
            cn = __builtin_amdgcn_mfma_f32_32x32x16_bf16(an0, bn0, Z, 0, 0, 0);
            EPI(ct, cn, tsA0, tsA1);
            ct = __builtin_amdgcn_mfma_f32_32x32x16_bf16(at1, bt0, Z, 0, 0, 0);
            cn = __builtin_amdgcn_mfma_f32_32x32x16_bf16(an1, bn0, Z, 0, 0, 0);
            EPI(ct, cn, tsB0, tsB1);

            // rotate pipeline (named registers; SSA renaming under unroll 2)
            bt0 = bt1; bn0 = bn1;
            bt1 = pt;  bn1 = pn;
        }
        acc = __builtin_fmaf(w, tsA0 + tsA1, acc);
        acc = __builtin_fmaf(w, tsB0 + tsB1, acc);
        vo = von; w = wn;
    }
#undef EPI

    // wave shuffle reduce -> 4 partials -> one atomic per block
    for (int off = 32; off; off >>= 1) acc += __shfl_down(acc, off, 64);
    __shared__ float partial[4];
    if ((tid & 63) == 0) partial[wid] = acc;
    __syncthreads();
    if (tid == 0)
        atomicAdd(out, (partial[0] + partial[1]) + (partial[2] + partial[3]));
}

extern "C" void kernel_launch(void* const* d_in, const int* in_sizes, int n_in,
                              void* d_out, int out_size, void* d_ws, size_t ws_size,
                              hipStream_t stream) {
    const float* sv = (const float*)d_in[0];
    const int*   si = (const int*)d_in[1];
    const float* tv = (const float*)d_in[2];
    const int*   ti = (const int*)d_in[3];
    const float* rn = (const float*)d_in[4];
    const float* rc = (const float*)d_in[5];
    float* out = (float*)d_out;
    u16*   ws  = (u16*)d_ws;                      // 2 x 24576 x 64 B = 3 MB features

    setup_feats<<<NPTS/256, 256, 0, stream>>>(sv, si, tv, ti, rn, rc, ws, out);
    dim3 grid(NXB, NYG);                          // 96 x 25 = 2400 blocks of 256
    energy_mfma<<<grid, 256, 0, stream>>>(ws, out);
}